// Round 15
// baseline (302.055 us; speedup 1.0000x reference)
//
#include <hip/hip_runtime.h>

#define MSG 64
#define SLICE_SHIFT 9      // 512 nodes per slice
#define SLICE_N (1 << SLICE_SHIFT)
#define MAXSLICES 256
#define REP 8              // cursor replicas per slice
#define CAP_R 1536         // edges per (slice,rep) aux region (mean 1024)
#define CAP_E 12288        // packed edges per slice (mean 8192, +45 sigma)
#define CAP_B 16384        // nodes per degree bucket
#define NBIN 64

typedef _Float16 h2 __attribute__((ext_vector_type(2)));
typedef _Float16 h4 __attribute__((ext_vector_type(4)));
typedef _Float16 h8 __attribute__((ext_vector_type(8)));

__device__ inline h8 relu8(h8 v) {
    h8 z = {};
    return __builtin_elementwise_max(v, z);
}

__device__ inline h2 u2h(unsigned u) { union { unsigned u; h2 h; } c; c.u = u; return c.h; }

// Fused setup, role-switched on blockIdx:
// [0,ab): tAi  [ab]: tBi  [ab+1,2ab+1): tAu  [2ab+1]: tBu  [2ab+2,2ab+10): wst
// [2ab+10]: gcur + bcnt   [2ab+11, 2ab+11+128): mol zero
__global__ void setup_kernel(const float* __restrict__ atom, const float* __restrict__ bond,
                             const float* __restrict__ Wi, const float* __restrict__ bi,
                             const float* __restrict__ Wu, const float* __restrict__ bu,
                             const float* __restrict__ Wagg,
                             _Float16* __restrict__ tAi, _Float16* __restrict__ tBi,
                             _Float16* __restrict__ tAu, _Float16* __restrict__ tBu,
                             unsigned* __restrict__ wst, int* __restrict__ gcur,
                             int* __restrict__ bcnt, float* __restrict__ mol,
                             int AR, int K, int ab) {
    int b = blockIdx.x;
    if (b < 2 * ab + 2) {
        bool upd = b >= ab + 1;
        const float* W = upd ? Wu : Wi;
        int lb = upd ? b - (ab + 1) : b;
        if (lb < ab) {
            _Float16* tA = upd ? tAu : tAi;
            int t = lb * 256 + threadIdx.x;
            if (t < AR * MSG) {
                int i = t & 63, a = t >> 6;
                float s = 0.f;
                for (int k = 0; k < 64; ++k) s = fmaf(atom[a * 64 + k], W[k * 64 + i], s);
                tA[t] = (_Float16)s;
            }
        } else {
            _Float16* tBo = upd ? tBu : tBi;
            const float* bias = upd ? bu : bi;
            const float* W16 = W + 64 * MSG;
            int t = threadIdx.x;
            int i = t & 63, r = t >> 6;
            float s = bias[i];
            for (int k = 0; k < 16; ++k) s = fmaf(bond[r * 16 + k], W16[k * 64 + i], s);
            tBo[t] = (_Float16)s;
        }
    } else if (b < 2 * ab + 10) {
        int t = (b - (2 * ab + 2)) * 256 + threadIdx.x;
        if (t < 2048) {
            int k2 = t >> 6, c = t & 63;
            h2 h; h[0] = (_Float16)Wagg[(2 * k2) * 64 + c]; h[1] = (_Float16)Wagg[(2 * k2 + 1) * 64 + c];
            union { h2 h; unsigned u; } cv; cv.h = h;
            wst[k2 * 64 + c] = cv.u;
        }
    } else if (b == 2 * ab + 10) {
        for (int q = threadIdx.x; q < K * REP; q += 256) gcur[q] = q * CAP_R;
        if (threadIdx.x < NBIN) bcnt[threadIdx.x] = 0;
    } else {
        int t = (b - (2 * ab + 11)) * 256 + threadIdx.x;   // 128 blocks x 256 x 16B = 512KB
        ((float4*)mol)[t] = make_float4(0.f, 0.f, 0.f, 0.f);
    }
}

// Phase 1: radix-partition with LDS RUN-STAGING for coalesced aux writes.
// record = pw(19b)<<17 | dst(17b), pw = src | eattr<<17.  slice = dst>>9.
__global__ __launch_bounds__(256) void partition_kernel(
    const int* __restrict__ ei, const int* __restrict__ eattr,
    int E, int* __restrict__ gcur, unsigned long long* __restrict__ aux, int K)
{
    __shared__ int cnt[MAXSLICES];
    __shared__ int lexcl[MAXSLICES];
    __shared__ int gbase[MAXSLICES];
    __shared__ int wsum[4];
    __shared__ unsigned long long stage[1024];
    if (threadIdx.x < MAXSLICES) cnt[threadIdx.x] = 0;
    __syncthreads();
    int rep = blockIdx.x & (REP - 1);
    int e0 = blockIdx.x * 1024;
    int total = min(1024, E - e0);
    int sl[4]; int rk[4]; unsigned long long rec[4];
#pragma unroll
    for (int r = 0; r < 4; ++r) {
        sl[r] = -1;
        int e = e0 + r * 256 + threadIdx.x;
        if (e < E) {
            int s = ei[e], d = ei[E + e];
            rec[r] = ((unsigned long long)((unsigned)s | ((unsigned)eattr[e] << 17)) << 17) | (unsigned)d;
            sl[r] = d >> SLICE_SHIFT;
            rk[r] = atomicAdd(&cnt[sl[r]], 1);
        }
    }
    __syncthreads();
    {
        int c = cnt[threadIdx.x];
        int lane = threadIdx.x & 63, w = threadIdx.x >> 6;
        int sc = c;
        for (int off = 1; off < 64; off <<= 1) { int t = __shfl_up(sc, off); if (lane >= off) sc += t; }
        if (lane == 63) wsum[w] = sc;
        __syncthreads();
        int add = 0;
        for (int q = 0; q < 3; ++q) if (w > q) add += wsum[q];
        lexcl[threadIdx.x] = sc + add - c;
        if (threadIdx.x < K && c > 0)
            gbase[threadIdx.x] = atomicAdd(&gcur[threadIdx.x * REP + rep], c);
    }
    __syncthreads();
#pragma unroll
    for (int r = 0; r < 4; ++r)
        if (sl[r] >= 0) stage[lexcl[sl[r]] + rk[r]] = rec[r];
    __syncthreads();
#pragma unroll
    for (int r = 0; r < 4; ++r) {
        int i = r * 256 + threadIdx.x;
        if (i < total) {
            unsigned long long a = stage[i];
            int s = (int)((unsigned)a & 0x1FFFFu) >> SLICE_SHIFT;
            aux[gbase[s] + (i - lexcl[s])] = a;
        }
    }
}

// Phase 2: one block OWNS one slice. Pass A: count + scan -> nstart (+deg).
// Pass B: scatter pw into LDS stage. Pass C: stream stage out linearly.
// Pass D: degree-bucket this slice's nodes: bucket entry = v | deg<<17.
__global__ __launch_bounds__(1024) void place_kernel(
    const unsigned long long* __restrict__ aux, const int* __restrict__ gcur,
    int* __restrict__ nstart, int* __restrict__ bcnt, int* __restrict__ bucket,
    unsigned* __restrict__ packed, int N)
{
    __shared__ int cnt[SLICE_N];
    __shared__ int wsum[8];
    __shared__ unsigned stage[CAP_E];
    __shared__ int bc[NBIN];
    __shared__ int bb[NBIN];
    int s = blockIdx.x;
    int lo = s << SLICE_SHIFT;
    if (threadIdx.x < SLICE_N) cnt[threadIdx.x] = 0;
    if (threadIdx.x >= SLICE_N && threadIdx.x < SLICE_N + NBIN) bc[threadIdx.x - SLICE_N] = 0;
    __syncthreads();
    for (int r = 0; r < REP; ++r) {
        int q = s * REP + r;
        int start = q * CAP_R, end = gcur[q];
        for (int idx = start + threadIdx.x; idx < end; idx += 1024)
            atomicAdd(&cnt[(int)(aux[idx] & 0x1FFFFu) & (SLICE_N - 1)], 1);
    }
    __syncthreads();
    int c = 0, sc = 0;
    if (threadIdx.x < SLICE_N) {
        c = cnt[threadIdx.x];
        int lane = threadIdx.x & 63, w = threadIdx.x >> 6;
        sc = c;
        for (int off = 1; off < 64; off <<= 1) { int t = __shfl_up(sc, off); if (lane >= off) sc += t; }
        if (lane == 63) wsum[w] = sc;
    }
    __syncthreads();
    int v = lo + threadIdx.x;
    int bin = -1, rk = 0;
    if (threadIdx.x < SLICE_N) {
        int w = threadIdx.x >> 6;
        int add = 0;
        for (int q = 0; q < 7; ++q) if (w > q) add += wsum[q];
        sc += add;
        if (v < N) {
            nstart[v] = s * CAP_E + sc - c;
            bin = min(c, NBIN - 1);
            rk = atomicAdd(&bc[bin], 1);
        }
    }
    __syncthreads();
    if (threadIdx.x < NBIN && bc[threadIdx.x] > 0)
        bb[threadIdx.x] = atomicAdd(&bcnt[threadIdx.x], bc[threadIdx.x]);
    __syncthreads();
    if (bin >= 0) bucket[bin * CAP_B + bb[bin] + rk] = v | (c << 17);
    if (threadIdx.x < SLICE_N) cnt[threadIdx.x] = sc - c;   // relative cursor
    __syncthreads();
    for (int r = 0; r < REP; ++r) {
        int q = s * REP + r;
        int start = q * CAP_R, end = gcur[q];
        for (int idx = start + threadIdx.x; idx < end; idx += 1024) {
            unsigned long long a = aux[idx];
            int d = (int)(a & 0x1FFFFu);
            int p = atomicAdd(&cnt[d & (SLICE_N - 1)], 1);
            stage[p] = (unsigned)(a >> 17);
        }
    }
    __syncthreads();
    int totale = cnt[SLICE_N - 1];
    for (int i = threadIdx.x; i < totale; i += 1024)
        packed[s * CAP_E + i] = stage[i];
}

// Compact buckets -> srt, DESCENDING degree (high-degree blocks launch first:
// no long-block grid tail). srt[v'] = {edge_start, v | deg<<17}.
__global__ void compact_kernel(const int* __restrict__ bucket, const int* __restrict__ bcnt,
                               const int* __restrict__ nstart, int2* __restrict__ srt) {
    __shared__ int sbase;
    int b = blockIdx.x;
    if (threadIdx.x == 0) {
        int run = 0;
        for (int i = b + 1; i < NBIN; ++i) run += bcnt[i];   // bins ABOVE b come first
        sbase = run;
    }
    __syncthreads();
    int n = bcnt[b], base = sbase;
    for (int i = threadIdx.x; i < n; i += 256) {
        int e = bucket[b * CAP_B + i];
        int v = e & 0x1FFFF;
        srt[base + i] = make_int2(nstart[v], e);
    }
}

// 8 lanes per node (h8), 32 nodes per block, DESCENDING-degree order via srt.
// 16 rows in flight (unroll-16 + unroll-8 + tail); nontemporal index loads.
// MODE 0 (pass 0): row = tAi[x[src]] (x L2-hit 400KB, tAi L1-hit 15KB).
// MODE 1 (mid): row = nodearr[src]. MODE 2 (final): as 1, raw acc out.
template <int MODE>
__global__ __launch_bounds__(256, 4) void gather_kernel(
    const unsigned* __restrict__ packed, const int2* __restrict__ srt,
    const _Float16* __restrict__ nodearr, const _Float16* __restrict__ tB,
    const unsigned* __restrict__ wst_g, const _Float16* __restrict__ tAu,
    const int* __restrict__ x, const _Float16* __restrict__ tAi,
    _Float16* __restrict__ out, int N)
{
    __shared__ _Float16 tbs[4 * 64];
    __shared__ unsigned wst[32 * 64];
    __shared__ _Float16 rowb[32][72];
    tbs[threadIdx.x] = tB[threadIdx.x];
    if (MODE != 2)
        for (int idx = threadIdx.x; idx < 2048; idx += 256) wst[idx] = wst_g[idx];
    __syncthreads();
    int t = blockIdx.x * 256 + threadIdx.x;
    int vi = t >> 3;
    int j = threadIdx.x & 7;
    int w = threadIdx.x >> 3;
    const h8* na8 = (const h8*)nodearr;
    const h8* tAi8 = (const h8*)tAi;
    const _Float16* tbsj = tbs + j * 8;
    auto ldrow = [&](unsigned q) -> h8 {
        if (MODE == 0) return tAi8[(long long)x[q & 0x1FFFFu] * 8 + j];
        else           return na8[(q & 0x1FFFFu) * 8 + j];
    };
    auto ldtb = [&](unsigned q) -> h8 { return *(const h8*)&tbsj[(q >> 17) * 64]; };
    h8 acc = {};
    int v = 0;
    bool valid = vi < N;
    if (valid) {
        int2 s2 = srt[vi];
        int e = s2.x;
        v = (int)((unsigned)s2.y & 0x1FFFFu);
        int end = e + (int)((unsigned)s2.y >> 17);
        for (; e + 15 < end; e += 16) {
            unsigned q0 = __builtin_nontemporal_load(&packed[e]);
            unsigned q1 = __builtin_nontemporal_load(&packed[e + 1]);
            unsigned q2 = __builtin_nontemporal_load(&packed[e + 2]);
            unsigned q3 = __builtin_nontemporal_load(&packed[e + 3]);
            unsigned q4 = __builtin_nontemporal_load(&packed[e + 4]);
            unsigned q5 = __builtin_nontemporal_load(&packed[e + 5]);
            unsigned q6 = __builtin_nontemporal_load(&packed[e + 6]);
            unsigned q7 = __builtin_nontemporal_load(&packed[e + 7]);
            unsigned q8 = __builtin_nontemporal_load(&packed[e + 8]);
            unsigned q9 = __builtin_nontemporal_load(&packed[e + 9]);
            unsigned qa = __builtin_nontemporal_load(&packed[e + 10]);
            unsigned qb = __builtin_nontemporal_load(&packed[e + 11]);
            unsigned qc = __builtin_nontemporal_load(&packed[e + 12]);
            unsigned qd = __builtin_nontemporal_load(&packed[e + 13]);
            unsigned qe = __builtin_nontemporal_load(&packed[e + 14]);
            unsigned qf = __builtin_nontemporal_load(&packed[e + 15]);
            h8 m0 = ldrow(q0), m1 = ldrow(q1), m2 = ldrow(q2), m3 = ldrow(q3);
            h8 m4 = ldrow(q4), m5 = ldrow(q5), m6 = ldrow(q6), m7 = ldrow(q7);
            h8 m8 = ldrow(q8), m9 = ldrow(q9), ma = ldrow(qa), mb = ldrow(qb);
            h8 mc = ldrow(qc), md = ldrow(qd), me = ldrow(qe), mf = ldrow(qf);
            h8 s0 = relu8(m0 + ldtb(q0)), s1 = relu8(m1 + ldtb(q1));
            h8 s2v = relu8(m2 + ldtb(q2)), s3 = relu8(m3 + ldtb(q3));
            h8 s4 = relu8(m4 + ldtb(q4)), s5 = relu8(m5 + ldtb(q5));
            h8 s6 = relu8(m6 + ldtb(q6)), s7 = relu8(m7 + ldtb(q7));
            h8 s8 = relu8(m8 + ldtb(q8)), s9 = relu8(m9 + ldtb(q9));
            h8 sa = relu8(ma + ldtb(qa)), sb = relu8(mb + ldtb(qb));
            h8 scv = relu8(mc + ldtb(qc)), sd = relu8(md + ldtb(qd));
            h8 se = relu8(me + ldtb(qe)), sf = relu8(mf + ldtb(qf));
            acc += (((s0 + s1) + (s2v + s3)) + ((s4 + s5) + (s6 + s7)))
                 + (((s8 + s9) + (sa + sb)) + ((scv + sd) + (se + sf)));
        }
        for (; e + 7 < end; e += 8) {
            unsigned q0 = __builtin_nontemporal_load(&packed[e]);
            unsigned q1 = __builtin_nontemporal_load(&packed[e + 1]);
            unsigned q2 = __builtin_nontemporal_load(&packed[e + 2]);
            unsigned q3 = __builtin_nontemporal_load(&packed[e + 3]);
            unsigned q4 = __builtin_nontemporal_load(&packed[e + 4]);
            unsigned q5 = __builtin_nontemporal_load(&packed[e + 5]);
            unsigned q6 = __builtin_nontemporal_load(&packed[e + 6]);
            unsigned q7 = __builtin_nontemporal_load(&packed[e + 7]);
            h8 m0 = ldrow(q0), m1 = ldrow(q1), m2 = ldrow(q2), m3 = ldrow(q3);
            h8 m4 = ldrow(q4), m5 = ldrow(q5), m6 = ldrow(q6), m7 = ldrow(q7);
            h8 s0 = relu8(m0 + ldtb(q0)), s1 = relu8(m1 + ldtb(q1));
            h8 s2v = relu8(m2 + ldtb(q2)), s3 = relu8(m3 + ldtb(q3));
            h8 s4 = relu8(m4 + ldtb(q4)), s5 = relu8(m5 + ldtb(q5));
            h8 s6 = relu8(m6 + ldtb(q6)), s7 = relu8(m7 + ldtb(q7));
            acc += ((s0 + s1) + (s2v + s3)) + ((s4 + s5) + (s6 + s7));
        }
        for (; e < end; ++e) {
            unsigned q0 = __builtin_nontemporal_load(&packed[e]);
            acc += relu8(ldrow(q0) + ldtb(q0));
        }
    }
    if (MODE == 2) {
        if (valid) ((h8*)out)[(long long)v * 8 + j] = acc;
        return;
    }
    *(h8*)&rowb[w][j * 8] = acc;
    __syncthreads();
    if (!valid) return;
    const h2* rp = (const h2*)&rowb[w][0];
    const unsigned* wj = wst + j * 8;
    float o0 = 0.f, o1 = 0.f, o2 = 0.f, o3 = 0.f, o4 = 0.f, o5 = 0.f, o6 = 0.f, o7 = 0.f;
#pragma unroll
    for (int k2 = 0; k2 < 32; ++k2) {
        h2 r = rp[k2];
        uint4 wa = *(const uint4*)&wj[k2 * 64];
        uint4 wb = *(const uint4*)&wj[k2 * 64 + 4];
        o0 = __builtin_amdgcn_fdot2(r, u2h(wa.x), o0, false);
        o1 = __builtin_amdgcn_fdot2(r, u2h(wa.y), o1, false);
        o2 = __builtin_amdgcn_fdot2(r, u2h(wa.z), o2, false);
        o3 = __builtin_amdgcn_fdot2(r, u2h(wa.w), o3, false);
        o4 = __builtin_amdgcn_fdot2(r, u2h(wb.x), o4, false);
        o5 = __builtin_amdgcn_fdot2(r, u2h(wb.y), o5, false);
        o6 = __builtin_amdgcn_fdot2(r, u2h(wb.z), o6, false);
        o7 = __builtin_amdgcn_fdot2(r, u2h(wb.w), o7, false);
    }
    h8 ta = ((const h8*)tAu)[x[v] * 8 + j];
    h8 o;
    o[0] = (_Float16)(o0 + (float)ta[0]); o[1] = (_Float16)(o1 + (float)ta[1]);
    o[2] = (_Float16)(o2 + (float)ta[2]); o[3] = (_Float16)(o3 + (float)ta[3]);
    o[4] = (_Float16)(o4 + (float)ta[4]); o[5] = (_Float16)(o5 + (float)ta[5]);
    o[6] = (_Float16)(o6 + (float)ta[6]); o[7] = (_Float16)(o7 + (float)ta[7]);
    ((h8*)out)[(long long)v * 8 + j] = o;
}

// batch is sorted: run-length accumulate, flush on mol change.
__global__ void mol_pool_kernel(const _Float16* __restrict__ ns, const int* __restrict__ batch,
                                float* __restrict__ mol, int N) {
    int g = (blockIdx.x * blockDim.x + threadIdx.x) >> 4;
    int j = threadIdx.x & 15;
    int n0 = g * 32;
    if (n0 >= N) return;
    int n1 = min(n0 + 32, N);
    const h4* ns4 = (const h4*)ns;
    int cur = batch[n0];
    float ax = 0.f, ay = 0.f, az = 0.f, aw = 0.f;
    for (int n = n0; n < n1; ++n) {
        int b = batch[n];
        if (b != cur) {
            float* mp = &mol[(long long)cur * 64 + j * 4];
            atomicAdd(mp + 0, ax); atomicAdd(mp + 1, ay);
            atomicAdd(mp + 2, az); atomicAdd(mp + 3, aw);
            ax = ay = az = aw = 0.f; cur = b;
        }
        h4 vv = ns4[(long long)n * 16 + j];
        ax += (float)vv.x; ay += (float)vv.y; az += (float)vv.z; aw += (float)vv.w;
    }
    float* mp = &mol[(long long)cur * 64 + j * 4];
    atomicAdd(mp + 0, ax); atomicAdd(mp + 1, ay);
    atomicAdd(mp + 2, az); atomicAdd(mp + 3, aw);
}

__global__ void head_kernel(const float* __restrict__ mol, const float* __restrict__ W1,
                            const float* __restrict__ b1, const float* __restrict__ W2,
                            const float* __restrict__ b2, float* __restrict__ out) {
    int g = blockIdx.x;
    int j = threadIdx.x;
    float s = b1[j];
#pragma unroll
    for (int k = 0; k < 64; ++k) s = fmaf(mol[g * 64 + k], W1[k * 128 + j], s);
    s = fmaxf(s, 0.0f) * W2[j];
    __shared__ float red[128];
    red[j] = s;
    __syncthreads();
    for (int off = 64; off > 0; off >>= 1) {
        if (j < off) red[j] += red[j + off];
        __syncthreads();
    }
    if (j == 0) out[g] = red[0] + b2[0];
}

extern "C" void kernel_launch(void* const* d_in, const int* in_sizes, int n_in,
                              void* d_out, int out_size, void* d_ws, size_t ws_size,
                              hipStream_t stream) {
    const int*   x          = (const int*)d_in[0];
    const int*   eattr      = (const int*)d_in[1];
    const int*   ei         = (const int*)d_in[2];
    const int*   batch      = (const int*)d_in[3];
    const float* atom_table = (const float*)d_in[4];
    const float* bond_table = (const float*)d_in[5];
    const float* Wi         = (const float*)d_in[6];
    const float* bi         = (const float*)d_in[7];
    const float* Wu         = (const float*)d_in[8];
    const float* bu         = (const float*)d_in[9];
    const float* W1         = (const float*)d_in[10];
    const float* b1         = (const float*)d_in[11];
    const float* W2         = (const float*)d_in[12];
    const float* b2         = (const float*)d_in[13];

    const int N = in_sizes[0];      // 100000
    const int E = in_sizes[1];      // 1600000
    const int M = out_size;         // 2048
    const int AR = in_sizes[4] / 64;                          // 119 atom rows
    const int K = (N + SLICE_N - 1) >> SLICE_SHIFT;           // 196 slices
    const int ab = (AR * MSG + 255) / 256;                    // 30 blocks per tabA

    char* ws = (char*)d_ws;
    size_t off_b = 0;
    auto alloc = [&](size_t bytes) -> void* {
        void* p = ws + off_b;
        off_b = (off_b + bytes + 255) & ~(size_t)255;
        return p;
    };
    size_t nbytes = (size_t)N * MSG * 2;                 // 12.8 MB
    size_t abytes = (size_t)K * REP * CAP_R * 8;         // 19.3 MB
    _Float16* bufA  = (_Float16*)alloc(nbytes);
    _Float16* bufB  = (_Float16*)alloc(nbytes > abytes ? nbytes : abytes);  // aliased w/ aux
    unsigned long long* aux = (unsigned long long*)bufB;   // dead before bufB first written
    unsigned* packed = (unsigned*)alloc((size_t)K * CAP_E * 4);   // 9.6 MB
    int*      nstart = (int*)alloc((size_t)N * 4);
    int2*     srt    = (int2*)alloc((size_t)N * 8);
    int*      bucket = (int*)alloc((size_t)NBIN * CAP_B * 4);
    int*      bcnt   = (int*)alloc((size_t)NBIN * 4);
    int*      gcur   = (int*)alloc((size_t)K * REP * 4);
    _Float16* tAi    = (_Float16*)alloc((size_t)AR * MSG * 2);
    _Float16* tBi    = (_Float16*)alloc((size_t)4 * MSG * 2);
    _Float16* tAu    = (_Float16*)alloc((size_t)AR * MSG * 2);
    _Float16* tBu    = (_Float16*)alloc((size_t)4 * MSG * 2);
    unsigned* wstb   = (unsigned*)alloc((size_t)32 * 64 * 4);
    float*    mol    = (float*)alloc((size_t)M * MSG * 4);
    (void)ws_size; (void)n_in;

    const float* Wagg = Wu + 80 * MSG;

    // ---- fused setup: tables + wst + gcur/bcnt + mol zero ----
    setup_kernel<<<2 * ab + 11 + 128, 256, 0, stream>>>(atom_table, bond_table, Wi, bi, Wu, bu, Wagg,
                                                        tAi, tBi, tAu, tBu, wstb, gcur, bcnt, mol,
                                                        AR, K, ab);

    // ---- CSR by dst: partition (run-staged) -> place (LDS-staged + fused dbin) ----
    partition_kernel<<<(E + 1023) / 1024, 256, 0, stream>>>(ei, eattr, E, gcur, aux, K);
    place_kernel<<<K, 1024, 0, stream>>>(aux, gcur, nstart, bcnt, bucket, packed, N);
    compact_kernel<<<NBIN, 256, 0, stream>>>(bucket, bcnt, nstart, srt);

    // ---- message passes: pass 0 reads x/tAi directly; descending-degree order ----
    const int gblocks = (int)(((long long)N * 8 + 255) / 256);
    gather_kernel<0><<<gblocks, 256, 0, stream>>>(packed, srt, nullptr, tBi, wstb, tAu, x, tAi, bufA, N);
    gather_kernel<1><<<gblocks, 256, 0, stream>>>(packed, srt, bufA, tBu, wstb, tAu, x, nullptr, bufB, N);
    gather_kernel<1><<<gblocks, 256, 0, stream>>>(packed, srt, bufB, tBu, wstb, tAu, x, nullptr, bufA, N);
    gather_kernel<1><<<gblocks, 256, 0, stream>>>(packed, srt, bufA, tBu, wstb, tAu, x, nullptr, bufB, N);
    gather_kernel<2><<<gblocks, 256, 0, stream>>>(packed, srt, bufB, tBu, nullptr, nullptr, nullptr, nullptr, bufA, N);

    // ---- readout ----
    mol_pool_kernel<<<(((N + 31) / 32) * 16 + 255) / 256, 256, 0, stream>>>(bufA, batch, mol, N);
    head_kernel<<<M, 128, 0, stream>>>(mol, W1, b1, W2, b2, (float*)d_out);
}

// Round 16
// 261.576 us; speedup vs baseline: 1.1548x; 1.1548x over previous
//
#include <hip/hip_runtime.h>

#define MSG 64
#define SLICE_SHIFT 9      // 512 nodes per slice
#define SLICE_N (1 << SLICE_SHIFT)
#define MAXSLICES 256
#define REP 8              // cursor replicas per slice
#define CAP_R 1536         // edges per (slice,rep) aux region (mean 1024)
#define CAP_E 12288        // packed edges per slice (mean 8192, +45 sigma)
#define CAP_B 16384        // nodes per degree bucket
#define NBIN 64

typedef _Float16 h2 __attribute__((ext_vector_type(2)));
typedef _Float16 h4 __attribute__((ext_vector_type(4)));
typedef _Float16 h8 __attribute__((ext_vector_type(8)));

__device__ inline h8 relu8(h8 v) {
    h8 z = {};
    return __builtin_elementwise_max(v, z);
}

__device__ inline h2 u2h(unsigned u) { union { unsigned u; h2 h; } c; c.u = u; return c.h; }

// Fused setup, role-switched on blockIdx:
// [0,ab): tAi  [ab]: tBi  [ab+1,2ab+1): tAu  [2ab+1]: tBu  [2ab+2,2ab+10): wst
// [2ab+10]: gcur + bcnt   [2ab+11, 2ab+11+128): mol zero
__global__ void setup_kernel(const float* __restrict__ atom, const float* __restrict__ bond,
                             const float* __restrict__ Wi, const float* __restrict__ bi,
                             const float* __restrict__ Wu, const float* __restrict__ bu,
                             const float* __restrict__ Wagg,
                             _Float16* __restrict__ tAi, _Float16* __restrict__ tBi,
                             _Float16* __restrict__ tAu, _Float16* __restrict__ tBu,
                             unsigned* __restrict__ wst, int* __restrict__ gcur,
                             int* __restrict__ bcnt, float* __restrict__ mol,
                             int AR, int K, int ab) {
    int b = blockIdx.x;
    if (b < 2 * ab + 2) {
        bool upd = b >= ab + 1;
        const float* W = upd ? Wu : Wi;
        int lb = upd ? b - (ab + 1) : b;
        if (lb < ab) {
            _Float16* tA = upd ? tAu : tAi;
            int t = lb * 256 + threadIdx.x;
            if (t < AR * MSG) {
                int i = t & 63, a = t >> 6;
                float s = 0.f;
                for (int k = 0; k < 64; ++k) s = fmaf(atom[a * 64 + k], W[k * 64 + i], s);
                tA[t] = (_Float16)s;
            }
        } else {
            _Float16* tBo = upd ? tBu : tBi;
            const float* bias = upd ? bu : bi;
            const float* W16 = W + 64 * MSG;
            int t = threadIdx.x;
            int i = t & 63, r = t >> 6;
            float s = bias[i];
            for (int k = 0; k < 16; ++k) s = fmaf(bond[r * 16 + k], W16[k * 64 + i], s);
            tBo[t] = (_Float16)s;
        }
    } else if (b < 2 * ab + 10) {
        int t = (b - (2 * ab + 2)) * 256 + threadIdx.x;
        if (t < 2048) {
            int k2 = t >> 6, c = t & 63;
            h2 h; h[0] = (_Float16)Wagg[(2 * k2) * 64 + c]; h[1] = (_Float16)Wagg[(2 * k2 + 1) * 64 + c];
            union { h2 h; unsigned u; } cv; cv.h = h;
            wst[k2 * 64 + c] = cv.u;
        }
    } else if (b == 2 * ab + 10) {
        for (int q = threadIdx.x; q < K * REP; q += 256) gcur[q] = q * CAP_R;
        if (threadIdx.x < NBIN) bcnt[threadIdx.x] = 0;
    } else {
        int t = (b - (2 * ab + 11)) * 256 + threadIdx.x;   // 128 blocks x 256 x 16B = 512KB
        ((float4*)mol)[t] = make_float4(0.f, 0.f, 0.f, 0.f);
    }
}

// Phase 1: radix-partition with LDS RUN-STAGING for coalesced aux writes.
// record = pw(19b)<<17 | dst(17b), pw = src | eattr<<17.  slice = dst>>9.
__global__ __launch_bounds__(256) void partition_kernel(
    const int* __restrict__ ei, const int* __restrict__ eattr,
    int E, int* __restrict__ gcur, unsigned long long* __restrict__ aux, int K)
{
    __shared__ int cnt[MAXSLICES];
    __shared__ int lexcl[MAXSLICES];
    __shared__ int gbase[MAXSLICES];
    __shared__ int wsum[4];
    __shared__ unsigned long long stage[1024];
    if (threadIdx.x < MAXSLICES) cnt[threadIdx.x] = 0;
    __syncthreads();
    int rep = blockIdx.x & (REP - 1);
    int e0 = blockIdx.x * 1024;
    int total = min(1024, E - e0);
    int sl[4]; int rk[4]; unsigned long long rec[4];
#pragma unroll
    for (int r = 0; r < 4; ++r) {
        sl[r] = -1;
        int e = e0 + r * 256 + threadIdx.x;
        if (e < E) {
            int s = ei[e], d = ei[E + e];
            rec[r] = ((unsigned long long)((unsigned)s | ((unsigned)eattr[e] << 17)) << 17) | (unsigned)d;
            sl[r] = d >> SLICE_SHIFT;
            rk[r] = atomicAdd(&cnt[sl[r]], 1);
        }
    }
    __syncthreads();
    {
        int c = cnt[threadIdx.x];
        int lane = threadIdx.x & 63, w = threadIdx.x >> 6;
        int sc = c;
        for (int off = 1; off < 64; off <<= 1) { int t = __shfl_up(sc, off); if (lane >= off) sc += t; }
        if (lane == 63) wsum[w] = sc;
        __syncthreads();
        int add = 0;
        for (int q = 0; q < 3; ++q) if (w > q) add += wsum[q];
        lexcl[threadIdx.x] = sc + add - c;
        if (threadIdx.x < K && c > 0)
            gbase[threadIdx.x] = atomicAdd(&gcur[threadIdx.x * REP + rep], c);
    }
    __syncthreads();
#pragma unroll
    for (int r = 0; r < 4; ++r)
        if (sl[r] >= 0) stage[lexcl[sl[r]] + rk[r]] = rec[r];
    __syncthreads();
#pragma unroll
    for (int r = 0; r < 4; ++r) {
        int i = r * 256 + threadIdx.x;
        if (i < total) {
            unsigned long long a = stage[i];
            int s = (int)((unsigned)a & 0x1FFFFu) >> SLICE_SHIFT;
            aux[gbase[s] + (i - lexcl[s])] = a;
        }
    }
}

// Phase 2: one block OWNS one slice. Pass A: count + scan -> nstart (+deg).
// Pass B: scatter pw into LDS stage. Pass C: stream stage out linearly.
// Pass D: degree-bucket this slice's nodes: bucket entry = v | deg<<17.
__global__ __launch_bounds__(1024) void place_kernel(
    const unsigned long long* __restrict__ aux, const int* __restrict__ gcur,
    int* __restrict__ nstart, int* __restrict__ bcnt, int* __restrict__ bucket,
    unsigned* __restrict__ packed, int N)
{
    __shared__ int cnt[SLICE_N];
    __shared__ int wsum[8];
    __shared__ unsigned stage[CAP_E];
    __shared__ int bc[NBIN];
    __shared__ int bb[NBIN];
    int s = blockIdx.x;
    int lo = s << SLICE_SHIFT;
    if (threadIdx.x < SLICE_N) cnt[threadIdx.x] = 0;
    if (threadIdx.x >= SLICE_N && threadIdx.x < SLICE_N + NBIN) bc[threadIdx.x - SLICE_N] = 0;
    __syncthreads();
    for (int r = 0; r < REP; ++r) {
        int q = s * REP + r;
        int start = q * CAP_R, end = gcur[q];
        for (int idx = start + threadIdx.x; idx < end; idx += 1024)
            atomicAdd(&cnt[(int)(aux[idx] & 0x1FFFFu) & (SLICE_N - 1)], 1);
    }
    __syncthreads();
    int c = 0, sc = 0;
    if (threadIdx.x < SLICE_N) {
        c = cnt[threadIdx.x];
        int lane = threadIdx.x & 63, w = threadIdx.x >> 6;
        sc = c;
        for (int off = 1; off < 64; off <<= 1) { int t = __shfl_up(sc, off); if (lane >= off) sc += t; }
        if (lane == 63) wsum[w] = sc;
    }
    __syncthreads();
    int v = lo + threadIdx.x;
    int bin = -1, rk = 0;
    if (threadIdx.x < SLICE_N) {
        int w = threadIdx.x >> 6;
        int add = 0;
        for (int q = 0; q < 7; ++q) if (w > q) add += wsum[q];
        sc += add;
        if (v < N) {
            nstart[v] = s * CAP_E + sc - c;
            bin = min(c, NBIN - 1);
            rk = atomicAdd(&bc[bin], 1);
        }
    }
    __syncthreads();
    if (threadIdx.x < NBIN && bc[threadIdx.x] > 0)
        bb[threadIdx.x] = atomicAdd(&bcnt[threadIdx.x], bc[threadIdx.x]);
    __syncthreads();
    if (bin >= 0) bucket[bin * CAP_B + bb[bin] + rk] = v | (c << 17);
    if (threadIdx.x < SLICE_N) cnt[threadIdx.x] = sc - c;   // relative cursor
    __syncthreads();
    for (int r = 0; r < REP; ++r) {
        int q = s * REP + r;
        int start = q * CAP_R, end = gcur[q];
        for (int idx = start + threadIdx.x; idx < end; idx += 1024) {
            unsigned long long a = aux[idx];
            int d = (int)(a & 0x1FFFFu);
            int p = atomicAdd(&cnt[d & (SLICE_N - 1)], 1);
            stage[p] = (unsigned)(a >> 17);
        }
    }
    __syncthreads();
    int totale = cnt[SLICE_N - 1];
    for (int i = threadIdx.x; i < totale; i += 1024)
        packed[s * CAP_E + i] = stage[i];
}

// Compact buckets -> srt, DESCENDING degree (high-degree blocks launch first:
// no long-block grid tail). srt[v'] = {edge_start, v | deg<<17}.
__global__ void compact_kernel(const int* __restrict__ bucket, const int* __restrict__ bcnt,
                               const int* __restrict__ nstart, int2* __restrict__ srt) {
    __shared__ int sbase;
    int b = blockIdx.x;
    if (threadIdx.x == 0) {
        int run = 0;
        for (int i = b + 1; i < NBIN; ++i) run += bcnt[i];   // bins ABOVE b come first
        sbase = run;
    }
    __syncthreads();
    int n = bcnt[b], base = sbase;
    for (int i = threadIdx.x; i < n; i += 256) {
        int e = bucket[b * CAP_B + i];
        int v = e & 0x1FFFF;
        srt[base + i] = make_int2(nstart[v], e);
    }
}

// 8 lanes per node (h8), 32 nodes per block, DESCENDING-degree order via srt.
// unroll-8, plain cached loads, launch_bounds(256,8) — R14's proven config.
// MODE 0 (pass 0): row = tAi[x[src]] (x L2-hit 400KB, tAi L1-hit 15KB).
// MODE 1 (mid): row = nodearr[src]. MODE 2 (final): as 1, raw acc out.
template <int MODE>
__global__ __launch_bounds__(256, 8) void gather_kernel(
    const unsigned* __restrict__ packed, const int2* __restrict__ srt,
    const _Float16* __restrict__ nodearr, const _Float16* __restrict__ tB,
    const unsigned* __restrict__ wst_g, const _Float16* __restrict__ tAu,
    const int* __restrict__ x, const _Float16* __restrict__ tAi,
    _Float16* __restrict__ out, int N)
{
    __shared__ _Float16 tbs[4 * 64];
    __shared__ unsigned wst[32 * 64];
    __shared__ _Float16 rowb[32][72];
    tbs[threadIdx.x] = tB[threadIdx.x];
    if (MODE != 2)
        for (int idx = threadIdx.x; idx < 2048; idx += 256) wst[idx] = wst_g[idx];
    __syncthreads();
    int t = blockIdx.x * 256 + threadIdx.x;
    int vi = t >> 3;
    int j = threadIdx.x & 7;
    int w = threadIdx.x >> 3;
    const h8* na8 = (const h8*)nodearr;
    const h8* tAi8 = (const h8*)tAi;
    const _Float16* tbsj = tbs + j * 8;
    auto ldrow = [&](unsigned q) -> h8 {
        if (MODE == 0) return tAi8[(long long)x[q & 0x1FFFFu] * 8 + j];
        else           return na8[(q & 0x1FFFFu) * 8 + j];
    };
    auto ldtb = [&](unsigned q) -> h8 { return *(const h8*)&tbsj[(q >> 17) * 64]; };
    h8 acc = {};
    int v = 0;
    bool valid = vi < N;
    if (valid) {
        int2 s2 = srt[vi];
        int e = s2.x;
        v = (int)((unsigned)s2.y & 0x1FFFFu);
        int end = e + (int)((unsigned)s2.y >> 17);
        for (; e + 7 < end; e += 8) {
            unsigned q0 = packed[e],     q1 = packed[e + 1], q2 = packed[e + 2], q3 = packed[e + 3];
            unsigned q4 = packed[e + 4], q5 = packed[e + 5], q6 = packed[e + 6], q7 = packed[e + 7];
            h8 m0 = ldrow(q0), m1 = ldrow(q1), m2 = ldrow(q2), m3 = ldrow(q3);
            h8 m4 = ldrow(q4), m5 = ldrow(q5), m6 = ldrow(q6), m7 = ldrow(q7);
            h8 s0 = relu8(m0 + ldtb(q0)), s1 = relu8(m1 + ldtb(q1));
            h8 s2v = relu8(m2 + ldtb(q2)), s3 = relu8(m3 + ldtb(q3));
            h8 s4 = relu8(m4 + ldtb(q4)), s5 = relu8(m5 + ldtb(q5));
            h8 s6 = relu8(m6 + ldtb(q6)), s7 = relu8(m7 + ldtb(q7));
            acc += ((s0 + s1) + (s2v + s3)) + ((s4 + s5) + (s6 + s7));
        }
        for (; e < end; ++e) {
            unsigned q0 = packed[e];
            acc += relu8(ldrow(q0) + ldtb(q0));
        }
    }
    if (MODE == 2) {
        if (valid) ((h8*)out)[(long long)v * 8 + j] = acc;
        return;
    }
    *(h8*)&rowb[w][j * 8] = acc;
    __syncthreads();
    if (!valid) return;
    const h2* rp = (const h2*)&rowb[w][0];
    const unsigned* wj = wst + j * 8;
    float o0 = 0.f, o1 = 0.f, o2 = 0.f, o3 = 0.f, o4 = 0.f, o5 = 0.f, o6 = 0.f, o7 = 0.f;
#pragma unroll
    for (int k2 = 0; k2 < 32; ++k2) {
        h2 r = rp[k2];
        uint4 wa = *(const uint4*)&wj[k2 * 64];
        uint4 wb = *(const uint4*)&wj[k2 * 64 + 4];
        o0 = __builtin_amdgcn_fdot2(r, u2h(wa.x), o0, false);
        o1 = __builtin_amdgcn_fdot2(r, u2h(wa.y), o1, false);
        o2 = __builtin_amdgcn_fdot2(r, u2h(wa.z), o2, false);
        o3 = __builtin_amdgcn_fdot2(r, u2h(wa.w), o3, false);
        o4 = __builtin_amdgcn_fdot2(r, u2h(wb.x), o4, false);
        o5 = __builtin_amdgcn_fdot2(r, u2h(wb.y), o5, false);
        o6 = __builtin_amdgcn_fdot2(r, u2h(wb.z), o6, false);
        o7 = __builtin_amdgcn_fdot2(r, u2h(wb.w), o7, false);
    }
    h8 ta = ((const h8*)tAu)[x[v] * 8 + j];
    h8 o;
    o[0] = (_Float16)(o0 + (float)ta[0]); o[1] = (_Float16)(o1 + (float)ta[1]);
    o[2] = (_Float16)(o2 + (float)ta[2]); o[3] = (_Float16)(o3 + (float)ta[3]);
    o[4] = (_Float16)(o4 + (float)ta[4]); o[5] = (_Float16)(o5 + (float)ta[5]);
    o[6] = (_Float16)(o6 + (float)ta[6]); o[7] = (_Float16)(o7 + (float)ta[7]);
    ((h8*)out)[(long long)v * 8 + j] = o;
}

// batch is sorted: run-length accumulate, flush on mol change.
__global__ void mol_pool_kernel(const _Float16* __restrict__ ns, const int* __restrict__ batch,
                                float* __restrict__ mol, int N) {
    int g = (blockIdx.x * blockDim.x + threadIdx.x) >> 4;
    int j = threadIdx.x & 15;
    int n0 = g * 32;
    if (n0 >= N) return;
    int n1 = min(n0 + 32, N);
    const h4* ns4 = (const h4*)ns;
    int cur = batch[n0];
    float ax = 0.f, ay = 0.f, az = 0.f, aw = 0.f;
    for (int n = n0; n < n1; ++n) {
        int b = batch[n];
        if (b != cur) {
            float* mp = &mol[(long long)cur * 64 + j * 4];
            atomicAdd(mp + 0, ax); atomicAdd(mp + 1, ay);
            atomicAdd(mp + 2, az); atomicAdd(mp + 3, aw);
            ax = ay = az = aw = 0.f; cur = b;
        }
        h4 vv = ns4[(long long)n * 16 + j];
        ax += (float)vv.x; ay += (float)vv.y; az += (float)vv.z; aw += (float)vv.w;
    }
    float* mp = &mol[(long long)cur * 64 + j * 4];
    atomicAdd(mp + 0, ax); atomicAdd(mp + 1, ay);
    atomicAdd(mp + 2, az); atomicAdd(mp + 3, aw);
}

__global__ void head_kernel(const float* __restrict__ mol, const float* __restrict__ W1,
                            const float* __restrict__ b1, const float* __restrict__ W2,
                            const float* __restrict__ b2, float* __restrict__ out) {
    int g = blockIdx.x;
    int j = threadIdx.x;
    float s = b1[j];
#pragma unroll
    for (int k = 0; k < 64; ++k) s = fmaf(mol[g * 64 + k], W1[k * 128 + j], s);
    s = fmaxf(s, 0.0f) * W2[j];
    __shared__ float red[128];
    red[j] = s;
    __syncthreads();
    for (int off = 64; off > 0; off >>= 1) {
        if (j < off) red[j] += red[j + off];
        __syncthreads();
    }
    if (j == 0) out[g] = red[0] + b2[0];
}

extern "C" void kernel_launch(void* const* d_in, const int* in_sizes, int n_in,
                              void* d_out, int out_size, void* d_ws, size_t ws_size,
                              hipStream_t stream) {
    const int*   x          = (const int*)d_in[0];
    const int*   eattr      = (const int*)d_in[1];
    const int*   ei         = (const int*)d_in[2];
    const int*   batch      = (const int*)d_in[3];
    const float* atom_table = (const float*)d_in[4];
    const float* bond_table = (const float*)d_in[5];
    const float* Wi         = (const float*)d_in[6];
    const float* bi         = (const float*)d_in[7];
    const float* Wu         = (const float*)d_in[8];
    const float* bu         = (const float*)d_in[9];
    const float* W1         = (const float*)d_in[10];
    const float* b1         = (const float*)d_in[11];
    const float* W2         = (const float*)d_in[12];
    const float* b2         = (const float*)d_in[13];

    const int N = in_sizes[0];      // 100000
    const int E = in_sizes[1];      // 1600000
    const int M = out_size;         // 2048
    const int AR = in_sizes[4] / 64;                          // 119 atom rows
    const int K = (N + SLICE_N - 1) >> SLICE_SHIFT;           // 196 slices
    const int ab = (AR * MSG + 255) / 256;                    // 30 blocks per tabA

    char* ws = (char*)d_ws;
    size_t off_b = 0;
    auto alloc = [&](size_t bytes) -> void* {
        void* p = ws + off_b;
        off_b = (off_b + bytes + 255) & ~(size_t)255;
        return p;
    };
    size_t nbytes = (size_t)N * MSG * 2;                 // 12.8 MB
    size_t abytes = (size_t)K * REP * CAP_R * 8;         // 19.3 MB
    _Float16* bufA  = (_Float16*)alloc(nbytes);
    _Float16* bufB  = (_Float16*)alloc(nbytes > abytes ? nbytes : abytes);  // aliased w/ aux
    unsigned long long* aux = (unsigned long long*)bufB;   // dead before bufB first written
    unsigned* packed = (unsigned*)alloc((size_t)K * CAP_E * 4);   // 9.6 MB
    int*      nstart = (int*)alloc((size_t)N * 4);
    int2*     srt    = (int2*)alloc((size_t)N * 8);
    int*      bucket = (int*)alloc((size_t)NBIN * CAP_B * 4);
    int*      bcnt   = (int*)alloc((size_t)NBIN * 4);
    int*      gcur   = (int*)alloc((size_t)K * REP * 4);
    _Float16* tAi    = (_Float16*)alloc((size_t)AR * MSG * 2);
    _Float16* tBi    = (_Float16*)alloc((size_t)4 * MSG * 2);
    _Float16* tAu    = (_Float16*)alloc((size_t)AR * MSG * 2);
    _Float16* tBu    = (_Float16*)alloc((size_t)4 * MSG * 2);
    unsigned* wstb   = (unsigned*)alloc((size_t)32 * 64 * 4);
    float*    mol    = (float*)alloc((size_t)M * MSG * 4);
    (void)ws_size; (void)n_in;

    const float* Wagg = Wu + 80 * MSG;

    // ---- fused setup: tables + wst + gcur/bcnt + mol zero ----
    setup_kernel<<<2 * ab + 11 + 128, 256, 0, stream>>>(atom_table, bond_table, Wi, bi, Wu, bu, Wagg,
                                                        tAi, tBi, tAu, tBu, wstb, gcur, bcnt, mol,
                                                        AR, K, ab);

    // ---- CSR by dst: partition (run-staged) -> place (LDS-staged + fused dbin) ----
    partition_kernel<<<(E + 1023) / 1024, 256, 0, stream>>>(ei, eattr, E, gcur, aux, K);
    place_kernel<<<K, 1024, 0, stream>>>(aux, gcur, nstart, bcnt, bucket, packed, N);
    compact_kernel<<<NBIN, 256, 0, stream>>>(bucket, bcnt, nstart, srt);

    // ---- message passes: pass 0 reads x/tAi directly; descending-degree order ----
    const int gblocks = (int)(((long long)N * 8 + 255) / 256);
    gather_kernel<0><<<gblocks, 256, 0, stream>>>(packed, srt, nullptr, tBi, wstb, tAu, x, tAi, bufA, N);
    gather_kernel<1><<<gblocks, 256, 0, stream>>>(packed, srt, bufA, tBu, wstb, tAu, x, nullptr, bufB, N);
    gather_kernel<1><<<gblocks, 256, 0, stream>>>(packed, srt, bufB, tBu, wstb, tAu, x, nullptr, bufA, N);
    gather_kernel<1><<<gblocks, 256, 0, stream>>>(packed, srt, bufA, tBu, wstb, tAu, x, nullptr, bufB, N);
    gather_kernel<2><<<gblocks, 256, 0, stream>>>(packed, srt, bufB, tBu, nullptr, nullptr, nullptr, nullptr, bufA, N);

    // ---- readout ----
    mol_pool_kernel<<<(((N + 31) / 32) * 16 + 255) / 256, 256, 0, stream>>>(bufA, batch, mol, N);
    head_kernel<<<M, 128, 0, stream>>>(mol, W1, b1, W2, b2, (float*)d_out);
}

// Round 17
// 252.688 us; speedup vs baseline: 1.1954x; 1.0352x over previous
//
#include <hip/hip_runtime.h>

#define MSG 64
#define SLICE_SHIFT 9      // 512 nodes per slice
#define SLICE_N (1 << SLICE_SHIFT)
#define MAXSLICES 256
#define REP 8              // cursor replicas per slice
#define CAP_R 1536         // edges per (slice,rep) aux region (mean 1024)
#define CAP_E 12288        // packed edges per slice (mean 8192, +45 sigma)
#define CAP_B 16384        // nodes per degree bucket
#define NBIN 64

typedef _Float16 h2 __attribute__((ext_vector_type(2)));
typedef _Float16 h4 __attribute__((ext_vector_type(4)));
typedef _Float16 h8 __attribute__((ext_vector_type(8)));

__device__ inline h8 relu8(h8 v) {
    h8 z = {};
    return __builtin_elementwise_max(v, z);
}

__device__ inline h2 u2h(unsigned u) { union { unsigned u; h2 h; } c; c.u = u; return c.h; }

// Fused setup, role-switched on blockIdx:
// [0,ab): tAi  [ab]: tBi  [ab+1,2ab+1): tAu  [2ab+1]: tBu  [2ab+2,2ab+10): wst
// [2ab+10]: gcur + bcnt   [2ab+11, 2ab+11+9): mstart (binary search over batch)
__global__ void setup_kernel(const float* __restrict__ atom, const float* __restrict__ bond,
                             const float* __restrict__ Wi, const float* __restrict__ bi,
                             const float* __restrict__ Wu, const float* __restrict__ bu,
                             const float* __restrict__ Wagg, const int* __restrict__ batch,
                             _Float16* __restrict__ tAi, _Float16* __restrict__ tBi,
                             _Float16* __restrict__ tAu, _Float16* __restrict__ tBu,
                             unsigned* __restrict__ wst, int* __restrict__ gcur,
                             int* __restrict__ bcnt, int* __restrict__ mstart,
                             int AR, int K, int ab, int N, int M) {
    int b = blockIdx.x;
    if (b < 2 * ab + 2) {
        bool upd = b >= ab + 1;
        const float* W = upd ? Wu : Wi;
        int lb = upd ? b - (ab + 1) : b;
        if (lb < ab) {
            _Float16* tA = upd ? tAu : tAi;
            int t = lb * 256 + threadIdx.x;
            if (t < AR * MSG) {
                int i = t & 63, a = t >> 6;
                float s = 0.f;
                for (int k = 0; k < 64; ++k) s = fmaf(atom[a * 64 + k], W[k * 64 + i], s);
                tA[t] = (_Float16)s;
            }
        } else {
            _Float16* tBo = upd ? tBu : tBi;
            const float* bias = upd ? bu : bi;
            const float* W16 = W + 64 * MSG;
            int t = threadIdx.x;
            int i = t & 63, r = t >> 6;
            float s = bias[i];
            for (int k = 0; k < 16; ++k) s = fmaf(bond[r * 16 + k], W16[k * 64 + i], s);
            tBo[t] = (_Float16)s;
        }
    } else if (b < 2 * ab + 10) {
        int t = (b - (2 * ab + 2)) * 256 + threadIdx.x;
        if (t < 2048) {
            int k2 = t >> 6, c = t & 63;
            h2 h; h[0] = (_Float16)Wagg[(2 * k2) * 64 + c]; h[1] = (_Float16)Wagg[(2 * k2 + 1) * 64 + c];
            union { h2 h; unsigned u; } cv; cv.h = h;
            wst[k2 * 64 + c] = cv.u;
        }
    } else if (b == 2 * ab + 10) {
        for (int q = threadIdx.x; q < K * REP; q += 256) gcur[q] = q * CAP_R;
        if (threadIdx.x < NBIN) bcnt[threadIdx.x] = 0;
    } else {
        int m = (b - (2 * ab + 11)) * 256 + threadIdx.x;
        if (m <= M) {   // mstart[m] = first index with batch[i] >= m; mstart[M] = N
            int lo = 0, hi = N;
            while (lo < hi) { int mid = (lo + hi) >> 1; if (batch[mid] < m) lo = mid + 1; else hi = mid; }
            mstart[m] = lo;
        }
    }
}

// Phase 1: radix-partition with LDS RUN-STAGING; 4-BYTE aux records.
// LDS stage holds u64 {slice<<32 | rec}; aux gets rec = pw(19b) | dstlo(9b)<<19,
// pw = src | eattr<<17.  slice = dst>>9.
__global__ __launch_bounds__(256) void partition_kernel(
    const int* __restrict__ ei, const int* __restrict__ eattr,
    int E, int* __restrict__ gcur, unsigned* __restrict__ aux, int K)
{
    __shared__ int cnt[MAXSLICES];
    __shared__ int lexcl[MAXSLICES];
    __shared__ int gbase[MAXSLICES];
    __shared__ int wsum[4];
    __shared__ unsigned long long stage[1024];
    if (threadIdx.x < MAXSLICES) cnt[threadIdx.x] = 0;
    __syncthreads();
    int rep = blockIdx.x & (REP - 1);
    int e0 = blockIdx.x * 1024;
    int total = min(1024, E - e0);
    int sl[4]; int rk[4]; unsigned long long rec[4];
#pragma unroll
    for (int r = 0; r < 4; ++r) {
        sl[r] = -1;
        int e = e0 + r * 256 + threadIdx.x;
        if (e < E) {
            int s = ei[e], d = ei[E + e];
            unsigned r32 = (unsigned)s | ((unsigned)eattr[e] << 17)
                         | ((unsigned)(d & (SLICE_N - 1)) << 19);
            sl[r] = d >> SLICE_SHIFT;
            rec[r] = ((unsigned long long)sl[r] << 32) | r32;
            rk[r] = atomicAdd(&cnt[sl[r]], 1);
        }
    }
    __syncthreads();
    {
        int c = cnt[threadIdx.x];
        int lane = threadIdx.x & 63, w = threadIdx.x >> 6;
        int sc = c;
        for (int off = 1; off < 64; off <<= 1) { int t = __shfl_up(sc, off); if (lane >= off) sc += t; }
        if (lane == 63) wsum[w] = sc;
        __syncthreads();
        int add = 0;
        for (int q = 0; q < 3; ++q) if (w > q) add += wsum[q];
        lexcl[threadIdx.x] = sc + add - c;
        if (threadIdx.x < K && c > 0)
            gbase[threadIdx.x] = atomicAdd(&gcur[threadIdx.x * REP + rep], c);
    }
    __syncthreads();
#pragma unroll
    for (int r = 0; r < 4; ++r)
        if (sl[r] >= 0) stage[lexcl[sl[r]] + rk[r]] = rec[r];
    __syncthreads();
#pragma unroll
    for (int r = 0; r < 4; ++r) {
        int i = r * 256 + threadIdx.x;
        if (i < total) {
            unsigned long long a = stage[i];
            int s = (int)(a >> 32);
            aux[gbase[s] + (i - lexcl[s])] = (unsigned)a;
        }
    }
}

// Phase 2: one block OWNS one slice. Pass A: count + scan -> nstart (+deg).
// Pass B: scatter pw into LDS stage. Pass C: stream stage out linearly.
// Pass D: degree-bucket this slice's nodes: bucket entry = v | deg<<17.
// aux records are 4B: dlo = (a>>19)&511, pw = a & 0x7FFFF.
__global__ __launch_bounds__(1024) void place_kernel(
    const unsigned* __restrict__ aux, const int* __restrict__ gcur,
    int* __restrict__ nstart, int* __restrict__ bcnt, int* __restrict__ bucket,
    unsigned* __restrict__ packed, int N)
{
    __shared__ int cnt[SLICE_N];
    __shared__ int wsum[8];
    __shared__ unsigned stage[CAP_E];
    __shared__ int bc[NBIN];
    __shared__ int bb[NBIN];
    int s = blockIdx.x;
    int lo = s << SLICE_SHIFT;
    if (threadIdx.x < SLICE_N) cnt[threadIdx.x] = 0;
    if (threadIdx.x >= SLICE_N && threadIdx.x < SLICE_N + NBIN) bc[threadIdx.x - SLICE_N] = 0;
    __syncthreads();
    for (int r = 0; r < REP; ++r) {
        int q = s * REP + r;
        int start = q * CAP_R, end = gcur[q];
        for (int idx = start + threadIdx.x; idx < end; idx += 1024)
            atomicAdd(&cnt[(aux[idx] >> 19) & (SLICE_N - 1)], 1);
    }
    __syncthreads();
    int c = 0, sc = 0;
    if (threadIdx.x < SLICE_N) {
        c = cnt[threadIdx.x];
        int lane = threadIdx.x & 63, w = threadIdx.x >> 6;
        sc = c;
        for (int off = 1; off < 64; off <<= 1) { int t = __shfl_up(sc, off); if (lane >= off) sc += t; }
        if (lane == 63) wsum[w] = sc;
    }
    __syncthreads();
    int v = lo + threadIdx.x;
    int bin = -1, rk = 0;
    if (threadIdx.x < SLICE_N) {
        int w = threadIdx.x >> 6;
        int add = 0;
        for (int q = 0; q < 7; ++q) if (w > q) add += wsum[q];
        sc += add;
        if (v < N) {
            nstart[v] = s * CAP_E + sc - c;
            bin = min(c, NBIN - 1);
            rk = atomicAdd(&bc[bin], 1);
        }
    }
    __syncthreads();
    if (threadIdx.x < NBIN && bc[threadIdx.x] > 0)
        bb[threadIdx.x] = atomicAdd(&bcnt[threadIdx.x], bc[threadIdx.x]);
    __syncthreads();
    if (bin >= 0) bucket[bin * CAP_B + bb[bin] + rk] = v | (c << 17);
    if (threadIdx.x < SLICE_N) cnt[threadIdx.x] = sc - c;   // relative cursor
    __syncthreads();
    for (int r = 0; r < REP; ++r) {
        int q = s * REP + r;
        int start = q * CAP_R, end = gcur[q];
        for (int idx = start + threadIdx.x; idx < end; idx += 1024) {
            unsigned a = aux[idx];
            int dlo = (a >> 19) & (SLICE_N - 1);
            int p = atomicAdd(&cnt[dlo], 1);
            stage[p] = a & 0x7FFFFu;
        }
    }
    __syncthreads();
    int totale = cnt[SLICE_N - 1];
    for (int i = threadIdx.x; i < totale; i += 1024)
        packed[s * CAP_E + i] = stage[i];
}

// Compact buckets -> srt, DESCENDING degree (high-degree blocks launch first).
// srt[v'] = {edge_start, v | deg<<17}.
__global__ void compact_kernel(const int* __restrict__ bucket, const int* __restrict__ bcnt,
                               const int* __restrict__ nstart, int2* __restrict__ srt) {
    __shared__ int sbase;
    int b = blockIdx.x;
    if (threadIdx.x == 0) {
        int run = 0;
        for (int i = b + 1; i < NBIN; ++i) run += bcnt[i];   // bins ABOVE b come first
        sbase = run;
    }
    __syncthreads();
    int n = bcnt[b], base = sbase;
    for (int i = threadIdx.x; i < n; i += 256) {
        int e = bucket[b * CAP_B + i];
        int v = e & 0x1FFFF;
        srt[base + i] = make_int2(nstart[v], e);
    }
}

// 8 lanes per node (h8), 32 nodes per block, DESCENDING-degree order via srt.
// unroll-8, plain cached loads, launch_bounds(256,8) — R14's proven config.
// MODE 0 (pass 0): row = tAi[x[src]] (x L2-hit 400KB, tAi L1-hit 15KB).
// MODE 1 (mid): row = nodearr[src]. MODE 2 (final): as 1, raw acc out.
template <int MODE>
__global__ __launch_bounds__(256, 8) void gather_kernel(
    const unsigned* __restrict__ packed, const int2* __restrict__ srt,
    const _Float16* __restrict__ nodearr, const _Float16* __restrict__ tB,
    const unsigned* __restrict__ wst_g, const _Float16* __restrict__ tAu,
    const int* __restrict__ x, const _Float16* __restrict__ tAi,
    _Float16* __restrict__ out, int N)
{
    __shared__ _Float16 tbs[4 * 64];
    __shared__ unsigned wst[32 * 64];
    __shared__ _Float16 rowb[32][72];
    tbs[threadIdx.x] = tB[threadIdx.x];
    if (MODE != 2)
        for (int idx = threadIdx.x; idx < 2048; idx += 256) wst[idx] = wst_g[idx];
    __syncthreads();
    int t = blockIdx.x * 256 + threadIdx.x;
    int vi = t >> 3;
    int j = threadIdx.x & 7;
    int w = threadIdx.x >> 3;
    const h8* na8 = (const h8*)nodearr;
    const h8* tAi8 = (const h8*)tAi;
    const _Float16* tbsj = tbs + j * 8;
    auto ldrow = [&](unsigned q) -> h8 {
        if (MODE == 0) return tAi8[(long long)x[q & 0x1FFFFu] * 8 + j];
        else           return na8[(q & 0x1FFFFu) * 8 + j];
    };
    auto ldtb = [&](unsigned q) -> h8 { return *(const h8*)&tbsj[(q >> 17) * 64]; };
    h8 acc = {};
    int v = 0;
    bool valid = vi < N;
    if (valid) {
        int2 s2 = srt[vi];
        int e = s2.x;
        v = (int)((unsigned)s2.y & 0x1FFFFu);
        int end = e + (int)((unsigned)s2.y >> 17);
        for (; e + 7 < end; e += 8) {
            unsigned q0 = packed[e],     q1 = packed[e + 1], q2 = packed[e + 2], q3 = packed[e + 3];
            unsigned q4 = packed[e + 4], q5 = packed[e + 5], q6 = packed[e + 6], q7 = packed[e + 7];
            h8 m0 = ldrow(q0), m1 = ldrow(q1), m2 = ldrow(q2), m3 = ldrow(q3);
            h8 m4 = ldrow(q4), m5 = ldrow(q5), m6 = ldrow(q6), m7 = ldrow(q7);
            h8 s0 = relu8(m0 + ldtb(q0)), s1 = relu8(m1 + ldtb(q1));
            h8 s2v = relu8(m2 + ldtb(q2)), s3 = relu8(m3 + ldtb(q3));
            h8 s4 = relu8(m4 + ldtb(q4)), s5 = relu8(m5 + ldtb(q5));
            h8 s6 = relu8(m6 + ldtb(q6)), s7 = relu8(m7 + ldtb(q7));
            acc += ((s0 + s1) + (s2v + s3)) + ((s4 + s5) + (s6 + s7));
        }
        for (; e < end; ++e) {
            unsigned q0 = packed[e];
            acc += relu8(ldrow(q0) + ldtb(q0));
        }
    }
    if (MODE == 2) {
        if (valid) ((h8*)out)[(long long)v * 8 + j] = acc;
        return;
    }
    *(h8*)&rowb[w][j * 8] = acc;
    __syncthreads();
    if (!valid) return;
    const h2* rp = (const h2*)&rowb[w][0];
    const unsigned* wj = wst + j * 8;
    float o0 = 0.f, o1 = 0.f, o2 = 0.f, o3 = 0.f, o4 = 0.f, o5 = 0.f, o6 = 0.f, o7 = 0.f;
#pragma unroll
    for (int k2 = 0; k2 < 32; ++k2) {
        h2 r = rp[k2];
        uint4 wa = *(const uint4*)&wj[k2 * 64];
        uint4 wb = *(const uint4*)&wj[k2 * 64 + 4];
        o0 = __builtin_amdgcn_fdot2(r, u2h(wa.x), o0, false);
        o1 = __builtin_amdgcn_fdot2(r, u2h(wa.y), o1, false);
        o2 = __builtin_amdgcn_fdot2(r, u2h(wa.z), o2, false);
        o3 = __builtin_amdgcn_fdot2(r, u2h(wa.w), o3, false);
        o4 = __builtin_amdgcn_fdot2(r, u2h(wb.x), o4, false);
        o5 = __builtin_amdgcn_fdot2(r, u2h(wb.y), o5, false);
        o6 = __builtin_amdgcn_fdot2(r, u2h(wb.z), o6, false);
        o7 = __builtin_amdgcn_fdot2(r, u2h(wb.w), o7, false);
    }
    h8 ta = ((const h8*)tAu)[x[v] * 8 + j];
    h8 o;
    o[0] = (_Float16)(o0 + (float)ta[0]); o[1] = (_Float16)(o1 + (float)ta[1]);
    o[2] = (_Float16)(o2 + (float)ta[2]); o[3] = (_Float16)(o3 + (float)ta[3]);
    o[4] = (_Float16)(o4 + (float)ta[4]); o[5] = (_Float16)(o5 + (float)ta[5]);
    o[6] = (_Float16)(o6 + (float)ta[6]); o[7] = (_Float16)(o7 + (float)ta[7]);
    ((h8*)out)[(long long)v * 8 + j] = o;
}

// Fused molecule pool + head: one block (128 thr) per molecule.
// Phase A: coalesced feature-row sums over [mstart[g], mstart[g+1]) (no atomics).
// Phase B: h = relu(mol@W1+b1); out = h@W2+b2.
__global__ void mol_head_kernel(const _Float16* __restrict__ ns, const int* __restrict__ mstart,
                                const float* __restrict__ W1, const float* __restrict__ b1,
                                const float* __restrict__ W2, const float* __restrict__ b2,
                                float* __restrict__ out) {
    int g = blockIdx.x;
    int j = threadIdx.x;   // 0..127
    int n0 = mstart[g], n1 = mstart[g + 1];
    __shared__ float partial[128];
    __shared__ float molrow[64];
    int f = j & 63;
    int half = j >> 6;
    int mid = n0 + ((n1 - n0 + 1) >> 1);
    int ns_ = half ? mid : n0;
    int ne_ = half ? n1 : mid;
    float sum = 0.f;
    for (int n = ns_; n < ne_; ++n) sum += (float)ns[(long long)n * 64 + f];
    partial[j] = sum;
    __syncthreads();
    if (j < 64) molrow[j] = partial[j] + partial[j + 64];
    __syncthreads();
    float s = b1[j];
#pragma unroll
    for (int k = 0; k < 64; ++k) s = fmaf(molrow[k], W1[k * 128 + j], s);
    s = fmaxf(s, 0.0f) * W2[j];
    __shared__ float red[128];
    red[j] = s;
    __syncthreads();
    for (int off = 64; off > 0; off >>= 1) {
        if (j < off) red[j] += red[j + off];
        __syncthreads();
    }
    if (j == 0) out[g] = red[0] + b2[0];
}

extern "C" void kernel_launch(void* const* d_in, const int* in_sizes, int n_in,
                              void* d_out, int out_size, void* d_ws, size_t ws_size,
                              hipStream_t stream) {
    const int*   x          = (const int*)d_in[0];
    const int*   eattr      = (const int*)d_in[1];
    const int*   ei         = (const int*)d_in[2];
    const int*   batch      = (const int*)d_in[3];
    const float* atom_table = (const float*)d_in[4];
    const float* bond_table = (const float*)d_in[5];
    const float* Wi         = (const float*)d_in[6];
    const float* bi         = (const float*)d_in[7];
    const float* Wu         = (const float*)d_in[8];
    const float* bu         = (const float*)d_in[9];
    const float* W1         = (const float*)d_in[10];
    const float* b1         = (const float*)d_in[11];
    const float* W2         = (const float*)d_in[12];
    const float* b2         = (const float*)d_in[13];

    const int N = in_sizes[0];      // 100000
    const int E = in_sizes[1];      // 1600000
    const int M = out_size;         // 2048
    const int AR = in_sizes[4] / 64;                          // 119 atom rows
    const int K = (N + SLICE_N - 1) >> SLICE_SHIFT;           // 196 slices
    const int ab = (AR * MSG + 255) / 256;                    // 30 blocks per tabA

    char* ws = (char*)d_ws;
    size_t off_b = 0;
    auto alloc = [&](size_t bytes) -> void* {
        void* p = ws + off_b;
        off_b = (off_b + bytes + 255) & ~(size_t)255;
        return p;
    };
    size_t nbytes = (size_t)N * MSG * 2;                 // 12.8 MB
    size_t abytes = (size_t)K * REP * CAP_R * 4;         // 9.7 MB (4B records)
    _Float16* bufA  = (_Float16*)alloc(nbytes);
    _Float16* bufB  = (_Float16*)alloc(nbytes > abytes ? nbytes : abytes);  // aliased w/ aux
    unsigned* aux   = (unsigned*)bufB;   // dead before bufB first written
    unsigned* packed = (unsigned*)alloc((size_t)K * CAP_E * 4);   // 9.6 MB
    int*      nstart = (int*)alloc((size_t)N * 4);
    int2*     srt    = (int2*)alloc((size_t)N * 8);
    int*      bucket = (int*)alloc((size_t)NBIN * CAP_B * 4);
    int*      bcnt   = (int*)alloc((size_t)NBIN * 4);
    int*      gcur   = (int*)alloc((size_t)K * REP * 4);
    int*      mstart = (int*)alloc((size_t)(M + 1) * 4);
    _Float16* tAi    = (_Float16*)alloc((size_t)AR * MSG * 2);
    _Float16* tBi    = (_Float16*)alloc((size_t)4 * MSG * 2);
    _Float16* tAu    = (_Float16*)alloc((size_t)AR * MSG * 2);
    _Float16* tBu    = (_Float16*)alloc((size_t)4 * MSG * 2);
    unsigned* wstb   = (unsigned*)alloc((size_t)32 * 64 * 4);
    (void)ws_size; (void)n_in;

    const float* Wagg = Wu + 80 * MSG;

    // ---- fused setup: tables + wst + gcur/bcnt + mstart ----
    const int mblocks = (M + 256) / 256 + 1;   // covers m in [0, M]
    setup_kernel<<<2 * ab + 11 + mblocks, 256, 0, stream>>>(atom_table, bond_table, Wi, bi, Wu, bu,
                                                            Wagg, batch, tAi, tBi, tAu, tBu, wstb,
                                                            gcur, bcnt, mstart, AR, K, ab, N, M);

    // ---- CSR by dst: partition (4B records) -> place (LDS-staged + fused dbin) ----
    partition_kernel<<<(E + 1023) / 1024, 256, 0, stream>>>(ei, eattr, E, gcur, aux, K);
    place_kernel<<<K, 1024, 0, stream>>>(aux, gcur, nstart, bcnt, bucket, packed, N);
    compact_kernel<<<NBIN, 256, 0, stream>>>(bucket, bcnt, nstart, srt);

    // ---- message passes: pass 0 reads x/tAi directly; descending-degree order ----
    const int gblocks = (int)(((long long)N * 8 + 255) / 256);
    gather_kernel<0><<<gblocks, 256, 0, stream>>>(packed, srt, nullptr, tBi, wstb, tAu, x, tAi, bufA, N);
    gather_kernel<1><<<gblocks, 256, 0, stream>>>(packed, srt, bufA, tBu, wstb, tAu, x, nullptr, bufB, N);
    gather_kernel<1><<<gblocks, 256, 0, stream>>>(packed, srt, bufB, tBu, wstb, tAu, x, nullptr, bufA, N);
    gather_kernel<1><<<gblocks, 256, 0, stream>>>(packed, srt, bufA, tBu, wstb, tAu, x, nullptr, bufB, N);
    gather_kernel<2><<<gblocks, 256, 0, stream>>>(packed, srt, bufB, tBu, nullptr, nullptr, nullptr, nullptr, bufA, N);

    // ---- fused readout ----
    mol_head_kernel<<<M, 128, 0, stream>>>(bufA, mstart, W1, b1, W2, b2, (float*)d_out);
}